// Round 8
// baseline (636.229 us; speedup 1.0000x reference)
//
#include <hip/hip_runtime.h>

typedef __attribute__((ext_vector_type(8))) short bf16x8;
typedef __attribute__((ext_vector_type(4))) float f32x4;
typedef __attribute__((ext_vector_type(16))) float f32x16;
typedef unsigned short u16;
typedef unsigned int u32;

#define DI __device__ __forceinline__

constexpr int B_ = 32, CI = 256, LX = 5000, CO = 128, LO = 2500, KW = 9, LP = 2560;

DI float b2f(u16 u) { u32 x = ((u32)u) << 16; return __builtin_bit_cast(float, x); }
DI u16 f2b(float f) {
  u32 x = __builtin_bit_cast(u32, f);
  u32 r = (x + 0x7fffu + ((x >> 16) & 1u)) >> 16;  // RNE
  return (u16)r;
}
DI float elu(float v) { return v > 0.f ? v : expm1f(v); }

// ---------------- K0: conv weight prep -> coalesced layout + fp32 alpha
// wfmt[((kk*16 + cg)*128 + o)*16 + j16] = sign(w[o][cg*16+j16][kk])
__global__ __launch_bounds__(256) void k_prep_wq(const float* __restrict__ w, u16* __restrict__ wfmt,
                                                 float* __restrict__ alphaf) {
  int o = blockIdx.x;
  const float* wrow = w + o * CI * KW;  // w[o][i][k]
  float s = 0.f;
  for (int idx = threadIdx.x; idx < CI * KW; idx += 256) s += fabsf(wrow[idx]);
  __shared__ float red[256];
  red[threadIdx.x] = s;
  __syncthreads();
  for (int st = 128; st > 0; st >>= 1) {
    if (threadIdx.x < st) red[threadIdx.x] += red[threadIdx.x + st];
    __syncthreads();
  }
  if (threadIdx.x == 0) alphaf[o] = red[0] / (float)(CI * KW);
  for (int idx = threadIdx.x; idx < CI * KW; idx += 256) {
    int i = idx / KW, k = idx - i * KW;
    float v = wrow[idx];
    float sg = v > 0.f ? 1.f : (v < 0.f ? -1.f : 0.f);
    wfmt[(((k * 16) + (i >> 4)) * 128 + o) * 16 + (i & 15)] = f2b(sg);
  }
}

// ---------------- K0b: projection matrices: wThi/wTlo[n][k] (attn wo) + coalesced qkv wT3
__global__ __launch_bounds__(256) void k_prep_wT(const float* __restrict__ wq, const float* __restrict__ wk,
                                                 const float* __restrict__ wv, const float* __restrict__ wo,
                                                 u16* __restrict__ wThi, u16* __restrict__ wTlo,
                                                 u16* __restrict__ wT3) {
  const float* src[4] = {wq, wk, wv, wo};
  int mat = blockIdx.x;
  const float* m = src[mat];
  u16* dh = wThi + mat * CO * CO;
  u16* dl = wTlo + mat * CO * CO;
  for (int idx = threadIdx.x; idx < CO * CO; idx += 256) {
    int nn = idx >> 7, kkn = idx & 127;  // n_out, k_in
    float v = m[kkn * CO + nn];
    u16 hi = f2b(v);
    u16 lo = f2b(v - b2f(hi));
    dh[idx] = hi;
    dl[idx] = lo;
    if (mat < 3) {
      int nt = nn >> 4, n = nn & 15, ks = kkn >> 5, gj = kkn & 31;
      size_t base = (size_t)((mat * 4 + ks) * 8 + nt) * 1024 + n * 32 + gj;
      wT3[base] = hi;
      wT3[base + 512] = lo;
    }
  }
}

// ---------------- K1: conv implicit-GEMM v4. r6 wave layout (8 waves x 32o x 32l) but ONE 37KB
// plane buffer staged 4x (cpass x hi/lo) -> 4 blocks/CU occupancy; single acc chain (hi+lo merged).
__global__ __launch_bounds__(512) void k_conv(const float* __restrict__ x, const u16* __restrict__ wfmt,
                                              const float* __restrict__ bias, const float* __restrict__ alphaf,
                                              float* __restrict__ y1) {
  const int ltile = blockIdx.x, b = blockIdx.y;
  const int l0 = ltile * 64;
  const int lin0 = 2 * l0 - 4;  // multiple of 4
  alignas(16) __shared__ u16 xs[136 * 136];  // one plane: [p][swizzled ch], 128 channels
  const int tid = threadIdx.x;
  const int wave = tid >> 6, lane = tid & 63;
  const int col = lane & 31, g = lane >> 5;
  const int o0 = (wave & 3) * 32;   // wave's 32 output channels
  const int lw = (wave >> 2) * 32;  // wave's l-offset inside the 64-wide tile
  f32x16 acc = {};                  // single chain: hi and lo passes accumulate into same C
  for (int pass = 0; pass < 4; ++pass) {
    const int cpass = pass >> 1, half = pass & 1;
    const int c0 = cpass * 128;
    if (pass) __syncthreads();  // prior pass's reads complete before overwrite
    for (int idx = tid; idx < 4352; idx += 512) {  // 128 ch x 34 float4
      int i = idx / 34, q = idx - i * 34;
      int lin = lin0 + q * 4;
      const float* xr = x + ((size_t)(b * CI + c0 + i)) * LX;
      float4 v4 = float4{0.f, 0.f, 0.f, 0.f};
      if (lin >= 0 && lin + 4 <= LX) v4 = *reinterpret_cast<const float4*>(xr + lin);
      const float* vp = reinterpret_cast<const float*>(&v4);
#pragma unroll
      for (int e = 0; e < 4; ++e) {
        int p = q * 4 + e;
        float v = vp[e];
        u16 hi = f2b(v);
        u16 val = half ? f2b(v - b2f(hi)) : hi;
        int colx = ((((i >> 3) ^ ((p >> 1) & 7)) << 3) | (i & 7));  // XOR-swizzle 16B blocks
        xs[p * 136 + colx] = val;
      }
    }
    __syncthreads();
    for (int kk = 0; kk < KW; ++kk) {
      bf16x8 af[8];
#pragma unroll
      for (int icg = 0; icg < 8; ++icg) {  // coalesced weight fragments (L2-resident)
        int chunk = kk * 16 + cpass * 8 + icg;
        af[icg] = *reinterpret_cast<const bf16x8*>(wfmt + ((size_t)chunk * 128 + o0 + col) * 16 + g * 8);
      }
      const int p = 2 * (lw + col) + kk;
      const int prow = p * 136;
      const int s = (p >> 1) & 7;
#pragma unroll
      for (int icg = 0; icg < 8; ++icg) {
        int blkoff = (((icg * 2 + g) ^ s) << 3);
        bf16x8 bv = *reinterpret_cast<const bf16x8*>(&xs[prow + blkoff]);
        acc = __builtin_amdgcn_mfma_f32_32x32x16_bf16(af[icg], bv, acc, 0, 0, 0);
      }
    }
  }
  const int l = l0 + lw + col;
  if (l < LO) {
#pragma unroll
    for (int r = 0; r < 16; ++r) {
      int o = o0 + (r & 3) + 8 * (r >> 2) + 4 * g;
      y1[(b * CO + o) * LO + l] = alphaf[o] * acc[r] + bias[o];
    }
  }
}

// ---------------- K2/K3: BN stats (deterministic two-stage)
__global__ __launch_bounds__(256) void k_stats(const float* __restrict__ y1, float* __restrict__ ps,
                                               float* __restrict__ ps2) {
  int o = blockIdx.x, b = blockIdx.y;
  const float* row = y1 + (b * CO + o) * LO;
  float s = 0.f, s2 = 0.f;
  for (int l = threadIdx.x; l < LO; l += 256) {
    float v = row[l];
    s += v;
    s2 += v * v;
  }
  __shared__ float r1[256], r2[256];
  r1[threadIdx.x] = s;
  r2[threadIdx.x] = s2;
  __syncthreads();
  for (int st = 128; st > 0; st >>= 1) {
    if (threadIdx.x < st) {
      r1[threadIdx.x] += r1[threadIdx.x + st];
      r2[threadIdx.x] += r2[threadIdx.x + st];
    }
    __syncthreads();
  }
  if (threadIdx.x == 0) {
    ps[b * CO + o] = r1[0];
    ps2[b * CO + o] = r2[0];
  }
}

__global__ void k_bnparams(const float* __restrict__ ps, const float* __restrict__ ps2,
                           const float* __restrict__ gamma, const float* __restrict__ beta,
                           float* __restrict__ bnsc, float* __restrict__ bnsh) {
  int o = threadIdx.x;
  float s = 0.f, s2 = 0.f;
  for (int b = 0; b < B_; ++b) {
    s += ps[b * CO + o];
    s2 += ps2[b * CO + o];
  }
  const float inv_n = 1.f / (float)(B_ * LO);
  float mu = s * inv_n;
  float var = s2 * inv_n - mu * mu;
  float sc = gamma[o] * rsqrtf(var + 1e-5f);
  bnsc[o] = sc;
  bnsh[o] = beta[o] - mu * sc;
}

// ---------------- K5: Q,K,V projections (BN+ELU fused into staging; bf16x4 split; coalesced wT3)
__global__ __launch_bounds__(256) void k_qkv(const float* __restrict__ y1, const float* __restrict__ bnsc,
                                             const float* __restrict__ bnsh, const u16* __restrict__ wT3,
                                             u16* __restrict__ sq, u16* __restrict__ sk, u16* __restrict__ sv) {
  int tile = blockIdx.x, b = blockIdx.y;
  int tid = threadIdx.x, wave = tid >> 6, lane = tid & 63, n = lane & 15, g = lane >> 4;
  const int t0 = tile * 64;
  alignas(16) __shared__ u16 hshi[64 * 136];
  alignas(16) __shared__ u16 hslo[64 * 136];
  {
    int t = tid & 63;
    int l = t0 + t;
    if (l > LO - 1) l = LO - 1;
    for (int c = (tid >> 6); c < CO; c += 4) {
      float raw = y1[((size_t)b * CO + c) * LO + l];
      float e = elu(raw * bnsc[c] + bnsh[c]);
      u16 hi = f2b(e);
      hshi[t * 136 + c] = hi;
      hslo[t * 136 + c] = f2b(e - b2f(hi));
    }
  }
  __syncthreads();
  const u16* ah = &hshi[(wave * 16 + n) * 136];
  const u16* al = &hslo[(wave * 16 + n) * 136];
  u16* outs[3] = {sq, sk, sv};
  for (int mat = 0; mat < 3; ++mat) {
    f32x4 acc[8] = {};
#pragma unroll
    for (int ks = 0; ks < 4; ++ks) {
      bf16x8 ahi = *reinterpret_cast<const bf16x8*>(ah + ks * 32 + g * 8);
      bf16x8 alo = *reinterpret_cast<const bf16x8*>(al + ks * 32 + g * 8);
      const u16* wbase = wT3 + (size_t)((mat * 4 + ks) * 8) * 1024 + n * 32 + g * 8;
#pragma unroll
      for (int nt = 0; nt < 8; ++nt) {
        bf16x8 bhi = *reinterpret_cast<const bf16x8*>(wbase + nt * 1024);
        bf16x8 blo = *reinterpret_cast<const bf16x8*>(wbase + nt * 1024 + 512);
        acc[nt] = __builtin_amdgcn_mfma_f32_16x16x32_bf16(ahi, bhi, acc[nt], 0, 0, 0);
        acc[nt] = __builtin_amdgcn_mfma_f32_16x16x32_bf16(ahi, blo, acc[nt], 0, 0, 0);
        acc[nt] = __builtin_amdgcn_mfma_f32_16x16x32_bf16(alo, bhi, acc[nt], 0, 0, 0);
        acc[nt] = __builtin_amdgcn_mfma_f32_16x16x32_bf16(alo, blo, acc[nt], 0, 0, 0);
      }
    }
    u16* so = outs[mat];
#pragma unroll
    for (int nt = 0; nt < 8; ++nt) {
#pragma unroll
      for (int r = 0; r < 4; ++r) {
        int tok = t0 + wave * 16 + g * 4 + r;
        int c = nt * 16 + n;
        bool valid = tok < LO;
        float v = valid ? acc[nt][r] : 0.f;
        so[((size_t)b * LP + tok) * CO + c] = f2b(v > 0.f ? 1.f : 0.f);
      }
    }
  }
}

// ---------------- K6: pool (BN+ELU fused) over global-attn chunks. One 64-lane block per (c,b) row.
__global__ __launch_bounds__(64) void k_poolh(const float* __restrict__ y1, const float* __restrict__ bnsc,
                                              const float* __restrict__ bnsh, float* __restrict__ hsum) {
  int c = blockIdx.x, b = blockIdx.y, lane = threadIdx.x;
  const float* row = y1 + ((size_t)b * CO + c) * LO;
  const float sc = bnsc[c], sh = bnsh[c];
  __shared__ float bins[16][64];
#pragma unroll
  for (int ch = 0; ch < 16; ++ch) bins[ch][lane] = 0.f;
  for (int j = lane; j < LO; j += 64) {
    float e = elu(row[j] * sc + sh);
    bins[j / 157][lane] += e;
  }
#pragma unroll
  for (int ch = 0; ch < 16; ++ch) {
    float v = bins[ch][lane];
    for (int off = 32; off > 0; off >>= 1) v += __shfl_down(v, off);
    if (lane == 0) hsum[(b * 16 + ch) * CO + c] = v;
  }
}

// ---------------- K7: pooled K/V spikes (fp32 exact) -> kvT[d][c] = (1/48)*sum_g skg[c]*svg[d]
__global__ __launch_bounds__(256) void k_kv2(const float* __restrict__ hsum, const float* __restrict__ wk,
                                             const float* __restrict__ wv, u16* __restrict__ kvT) {
  int b = blockIdx.x;
  __shared__ float hs[16 * 128], sks[16 * 128], svs[16 * 128];
  for (int i = threadIdx.x; i < 2048; i += 256) hs[i] = hsum[b * 2048 + i];
  __syncthreads();
  for (int idx = threadIdx.x; idx < 2048; idx += 256) {
    int gg = idx >> 7, c = idx & 127;
    float ak = 0.f, av = 0.f;
    for (int k = 0; k < 128; ++k) {
      float hv = hs[gg * 128 + k];
      ak += hv * wk[k * CO + c];
      av += hv * wv[k * CO + c];
    }
    sks[idx] = ak > 0.f ? 1.f : 0.f;
    svs[idx] = av > 0.f ? 1.f : 0.f;
  }
  __syncthreads();
  for (int idx = threadIdx.x; idx < CO * CO; idx += 256) {
    int d = idx >> 7, c = idx & 127;
    float s = 0.f;
#pragma unroll
    for (int gg = 0; gg < 16; ++gg) s += sks[gg * 128 + c] * svs[gg * 128 + d];
    kvT[b * CO * CO + idx] = f2b(s * (1.f / 48.f));
  }
}

// ---------------- K8: fused attention; residual recomputes BN+ELU from raw y1 in epilogue.
__global__ __launch_bounds__(512) void k_attn(const u16* __restrict__ sq, const u16* __restrict__ sk,
                                              const u16* __restrict__ sv, const u16* __restrict__ kvT,
                                              const u16* __restrict__ woT, const float* __restrict__ y1,
                                              const float* __restrict__ bnsc, const float* __restrict__ bnsh,
                                              float* __restrict__ out) {
  const int win = blockIdx.x, b = blockIdx.y, qt = blockIdx.z;
  const int T0 = win * 256;
  __shared__ u16 svT[128 * 264];      // svT[c][u]
  __shared__ u16 plds[8 * 16 * 264];  // per-wave [16 q][264 u] scratch (P, then attn-out)
  const int tid = threadIdx.x, wave = tid >> 6, lane = tid & 63, n = lane & 15, g = lane >> 4;
  for (int idx = tid; idx < 256 * 128; idx += 512) {
    int u = idx >> 7, c = idx & 127;
    svT[c * 264 + u] = sv[((size_t)b * LP + T0 + u) * CO + c];
  }
  __syncthreads();
  u16* pw = plds + wave * 16 * 264;
  {
    const int qbase = wave * 32 + qt * 16;
    bf16x8 bq[4];
    const u16* qrow = sq + ((size_t)b * LP + T0 + qbase + n) * CO;
#pragma unroll
    for (int ks = 0; ks < 4; ++ks) bq[ks] = *reinterpret_cast<const bf16x8*>(qrow + ks * 32 + g * 8);
    // phase A: S^T[u][q] = sum_k sk[u][k] * sq[q][k]
    f32x4 pacc[16];
#pragma unroll
    for (int ut = 0; ut < 16; ++ut) pacc[ut] = f32x4{0.f, 0.f, 0.f, 0.f};
    for (int ut = 0; ut < 16; ++ut) {
      const u16* krow = sk + ((size_t)b * LP + T0 + ut * 16 + n) * CO;
#pragma unroll
      for (int ks = 0; ks < 4; ++ks) {
        bf16x8 af = *reinterpret_cast<const bf16x8*>(krow + ks * 32 + g * 8);
        pacc[ut] = __builtin_amdgcn_mfma_f32_16x16x32_bf16(af, bq[ks], pacc[ut], 0, 0, 0);
      }
    }
    // phase A2: window weights (1/768 + 1/192 on diagonal 64-blocks), pack to LDS
    const int qloc = qbase + n;
    const int qblk = qloc >> 6;
#pragma unroll
    for (int ut = 0; ut < 16; ++ut) {
      u16 pk[4];
#pragma unroll
      for (int r = 0; r < 4; ++r) {
        int uloc = ut * 16 + g * 4 + r;
        float wgt = (1.f / 768.f) + (((uloc >> 6) == qblk) ? (1.f / 192.f) : 0.f);
        pk[r] = f2b(pacc[ut][r] * wgt);
      }
      unsigned long long pk64 = (unsigned long long)pk[0] | ((unsigned long long)pk[1] << 16) |
                                ((unsigned long long)pk[2] << 32) | ((unsigned long long)pk[3] << 48);
      *reinterpret_cast<unsigned long long*>(&pw[n * 264 + ut * 16 + g * 4]) = pk64;
    }
    __syncthreads();
    // phase B: PV (weighted); phase C: + global attn (kvT premultiplied by 1/48)
    f32x4 acco[8] = {};
    for (int us = 0; us < 8; ++us) {
      bf16x8 pa = *reinterpret_cast<const bf16x8*>(&pw[n * 264 + us * 32 + g * 8]);
#pragma unroll
      for (int ct = 0; ct < 8; ++ct) {
        bf16x8 bv = *reinterpret_cast<const bf16x8*>(&svT[(ct * 16 + n) * 264 + us * 32 + g * 8]);
        acco[ct] = __builtin_amdgcn_mfma_f32_16x16x32_bf16(pa, bv, acco[ct], 0, 0, 0);
      }
    }
#pragma unroll
    for (int ks = 0; ks < 4; ++ks) {
#pragma unroll
      for (int ct = 0; ct < 8; ++ct) {
        bf16x8 bkv = *reinterpret_cast<const bf16x8*>(kvT + ((size_t)b * CO + ct * 16 + n) * CO + ks * 32 + g * 8);
        acco[ct] = __builtin_amdgcn_mfma_f32_16x16x32_bf16(bq[ks], bkv, acco[ct], 0, 0, 0);
      }
    }
    // phase D: attn-out tile -> LDS (bf16)
#pragma unroll
    for (int ct = 0; ct < 8; ++ct) {
#pragma unroll
      for (int r = 0; r < 4; ++r) {
        pw[(g * 4 + r) * 264 + ct * 16 + n] = f2b(acco[ct][r]);
      }
    }
    __syncthreads();
    // phase E: y = elu(bn(y1)) + out@wo, store (B, Co, Lo)
#pragma unroll
    for (int ot = 0; ot < 8; ++ot) {
      f32x4 facc = {};
#pragma unroll
      for (int ks = 0; ks < 4; ++ks) {
        bf16x8 af = *reinterpret_cast<const bf16x8*>(&pw[n * 264 + ks * 32 + g * 8]);
        bf16x8 bw = *reinterpret_cast<const bf16x8*>(woT + (ot * 16 + n) * CO + ks * 32 + g * 8);
        facc = __builtin_amdgcn_mfma_f32_16x16x32_bf16(af, bw, facc, 0, 0, 0);
      }
      int o = ot * 16 + n;
      float sc = bnsc[o], sh = bnsh[o];
      int lb = T0 + qbase + g * 4;
#pragma unroll
      for (int r = 0; r < 4; ++r) {
        int l = lb + r;
        if (l < LO) {
          size_t idx = ((size_t)b * CO + o) * LO + l;
          out[idx] = elu(y1[idx] * sc + sh) + facc[r];
        }
      }
    }
  }
}

extern "C" void kernel_launch(void* const* d_in, const int* in_sizes, int n_in, void* d_out, int out_size,
                              void* d_ws, size_t ws_size, hipStream_t stream) {
  const float* x = (const float*)d_in[0];
  const float* conv_w = (const float*)d_in[1];
  const float* conv_b = (const float*)d_in[2];
  const float* gamma = (const float*)d_in[3];
  const float* beta = (const float*)d_in[4];
  const float* wq = (const float*)d_in[5];
  const float* wk = (const float*)d_in[6];
  const float* wv = (const float*)d_in[7];
  const float* wo = (const float*)d_in[8];
  (void)in_sizes; (void)n_in; (void)out_size; (void)ws_size;

  char* ws = (char*)d_ws;
  size_t off = 0;
  auto alloc = [&](size_t bytes) -> void* {
    void* p = ws + off;
    off += (bytes + 511) & ~(size_t)511;
    return p;
  };
  float* ps = (float*)alloc((size_t)B_ * CO * 4);
  float* ps2 = (float*)alloc((size_t)B_ * CO * 4);
  float* bnsc = (float*)alloc(CO * 4);
  float* bnsh = (float*)alloc(CO * 4);
  float* alphaf = (float*)alloc(CO * 4);
  float* hsum = (float*)alloc((size_t)B_ * 16 * CO * 4);
  u16* kvT = (u16*)alloc((size_t)B_ * CO * CO * 2);
  u16* wfmt = (u16*)alloc((size_t)CO * KW * CI * 2);
  u16* wThi = (u16*)alloc((size_t)4 * CO * CO * 2);
  u16* wTlo = (u16*)alloc((size_t)4 * CO * CO * 2);
  u16* wT3 = (u16*)alloc((size_t)3 * 4 * 8 * 1024 * 2);
  float* y1 = (float*)alloc((size_t)B_ * CO * LO * 4);
  u16* sqb = (u16*)alloc((size_t)B_ * LP * CO * 2);
  u16* skb = (u16*)alloc((size_t)B_ * LP * CO * 2);
  u16* svb = (u16*)alloc((size_t)B_ * LP * CO * 2);

  hipLaunchKernelGGL(k_prep_wq, dim3(CO), dim3(256), 0, stream, conv_w, wfmt, alphaf);
  hipLaunchKernelGGL(k_prep_wT, dim3(4), dim3(256), 0, stream, wq, wk, wv, wo, wThi, wTlo, wT3);
  hipLaunchKernelGGL(k_conv, dim3(40, B_), dim3(512), 0, stream, x, wfmt, conv_b, alphaf, y1);
  hipLaunchKernelGGL(k_stats, dim3(CO, B_), dim3(256), 0, stream, y1, ps, ps2);
  hipLaunchKernelGGL(k_bnparams, dim3(1), dim3(CO), 0, stream, ps, ps2, gamma, beta, bnsc, bnsh);
  hipLaunchKernelGGL(k_qkv, dim3(40, B_), dim3(256), 0, stream, y1, bnsc, bnsh, wT3, sqb, skb, svb);
  hipLaunchKernelGGL(k_poolh, dim3(CO, B_), dim3(64), 0, stream, y1, bnsc, bnsh, hsum);
  hipLaunchKernelGGL(k_kv2, dim3(B_), dim3(256), 0, stream, hsum, wk, wv, kvT);
  hipLaunchKernelGGL(k_attn, dim3(10, B_, 2), dim3(512), 0, stream, sqb, skb, svb, kvT, wThi + 3 * CO * CO, y1,
                     bnsc, bnsh, (float*)d_out);
}

// Round 9
// 517.164 us; speedup vs baseline: 1.2302x; 1.2302x over previous
//
#include <hip/hip_runtime.h>

typedef __attribute__((ext_vector_type(8))) short bf16x8;
typedef __attribute__((ext_vector_type(4))) float f32x4;
typedef __attribute__((ext_vector_type(16))) float f32x16;
typedef unsigned short u16;
typedef unsigned int u32;

#define DI __device__ __forceinline__

constexpr int B_ = 32, CI = 256, LX = 5000, CO = 128, LO = 2500, KW = 9, LP = 2560;

DI float b2f(u16 u) { u32 x = ((u32)u) << 16; return __builtin_bit_cast(float, x); }
DI u16 f2b(float f) {
  u32 x = __builtin_bit_cast(u32, f);
  u32 r = (x + 0x7fffu + ((x >> 16) & 1u)) >> 16;  // RNE
  return (u16)r;
}
DI float elu(float v) { return v > 0.f ? v : expm1f(v); }

// ---------------- K0: conv weight prep -> coalesced layout + fp32 alpha
// wfmt[((kk*16 + cg)*128 + o)*16 + j16] = sign(w[o][cg*16+j16][kk])
__global__ __launch_bounds__(256) void k_prep_wq(const float* __restrict__ w, u16* __restrict__ wfmt,
                                                 float* __restrict__ alphaf) {
  int o = blockIdx.x;
  const float* wrow = w + o * CI * KW;  // w[o][i][k]
  float s = 0.f;
  for (int idx = threadIdx.x; idx < CI * KW; idx += 256) s += fabsf(wrow[idx]);
  __shared__ float red[256];
  red[threadIdx.x] = s;
  __syncthreads();
  for (int st = 128; st > 0; st >>= 1) {
    if (threadIdx.x < st) red[threadIdx.x] += red[threadIdx.x + st];
    __syncthreads();
  }
  if (threadIdx.x == 0) alphaf[o] = red[0] / (float)(CI * KW);
  for (int idx = threadIdx.x; idx < CI * KW; idx += 256) {
    int i = idx / KW, k = idx - i * KW;
    float v = wrow[idx];
    float sg = v > 0.f ? 1.f : (v < 0.f ? -1.f : 0.f);
    wfmt[(((k * 16) + (i >> 4)) * 128 + o) * 16 + (i & 15)] = f2b(sg);
  }
}

// ---------------- K0b: projection matrices: wThi/wTlo[n][k] (attn wo) + coalesced qkv wT3
__global__ __launch_bounds__(256) void k_prep_wT(const float* __restrict__ wq, const float* __restrict__ wk,
                                                 const float* __restrict__ wv, const float* __restrict__ wo,
                                                 u16* __restrict__ wThi, u16* __restrict__ wTlo,
                                                 u16* __restrict__ wT3) {
  const float* src[4] = {wq, wk, wv, wo};
  int mat = blockIdx.x;
  const float* m = src[mat];
  u16* dh = wThi + mat * CO * CO;
  u16* dl = wTlo + mat * CO * CO;
  for (int idx = threadIdx.x; idx < CO * CO; idx += 256) {
    int nn = idx >> 7, kkn = idx & 127;  // n_out, k_in
    float v = m[kkn * CO + nn];
    u16 hi = f2b(v);
    u16 lo = f2b(v - b2f(hi));
    dh[idx] = hi;
    dl[idx] = lo;
    if (mat < 3) {
      int nt = nn >> 4, n = nn & 15, ks = kkn >> 5, gj = kkn & 31;
      size_t base = (size_t)((mat * 4 + ks) * 8 + nt) * 1024 + n * 32 + gj;
      wT3[base] = hi;
      wT3[base + 512] = lo;
    }
  }
}

// ---------------- K1: conv implicit-GEMM (r6-proven structure). 8 waves x (32o x 32l); dual hi/lo
// planes staged once per cpass; float4 staging loads; 4-bit XOR block swizzle (2-way = free).
__global__ __launch_bounds__(512) void k_conv(const float* __restrict__ x, const u16* __restrict__ wfmt,
                                              const float* __restrict__ bias, const float* __restrict__ alphaf,
                                              float* __restrict__ y1) {
  const int ltile = blockIdx.x, b = blockIdx.y;
  const int l0 = ltile * 64;
  const int lin0 = 2 * l0 - 4;  // multiple of 4
  alignas(16) __shared__ u16 xsh[136 * 136];  // hi plane [p][swizzled ch]
  alignas(16) __shared__ u16 xsl[136 * 136];  // lo plane
  const int tid = threadIdx.x;
  const int wave = tid >> 6, lane = tid & 63;
  const int col = lane & 31, g = lane >> 5;
  const int o0 = (wave & 3) * 32;   // wave's 32 output channels
  const int lw = (wave >> 2) * 32;  // wave's l-offset inside the 64-wide tile
  f32x16 acch = {};
  f32x16 accl = {};
  for (int cpass = 0; cpass < 2; ++cpass) {
    const int c0 = cpass * 128;
    if (cpass) __syncthreads();  // pass-0 reads complete before overwrite
#pragma unroll
    for (int it = 0; it < 9; ++it) {  // 4352 float4 = 128 ch x 34
      int idx = tid + it * 512;
      if (idx < 4352) {
        int i = idx / 34, q = idx - i * 34;
        int lin = lin0 + q * 4;
        const float* xr = x + ((size_t)(b * CI + c0 + i)) * LX;
        float4 v4 = float4{0.f, 0.f, 0.f, 0.f};
        if (lin >= 0 && lin + 4 <= LX) v4 = *reinterpret_cast<const float4*>(xr + lin);
        const float* vp = reinterpret_cast<const float*>(&v4);
#pragma unroll
        for (int e = 0; e < 4; ++e) {
          int p = q * 4 + e;
          float v = vp[e];
          u16 hi = f2b(v);
          int colx = ((((i >> 3) ^ ((p >> 1) & 15)) & 15) << 3) | (i & 7);  // 4-bit XOR swizzle
          xsh[p * 136 + colx] = hi;
          xsl[p * 136 + colx] = f2b(v - b2f(hi));
        }
      }
    }
    __syncthreads();
    for (int kk = 0; kk < KW; ++kk) {
      bf16x8 af[8];
#pragma unroll
      for (int icg = 0; icg < 8; ++icg) {  // coalesced weight fragments (L2-resident)
        int chunk = kk * 16 + cpass * 8 + icg;
        af[icg] = *reinterpret_cast<const bf16x8*>(wfmt + ((size_t)chunk * 128 + o0 + col) * 16 + g * 8);
      }
      const int p = 2 * (lw + col) + kk;
      const int prow = p * 136;
      const int s = (p >> 1) & 15;
#pragma unroll
      for (int icg = 0; icg < 8; ++icg) {
        int blkoff = (((icg * 2 + g) ^ s) << 3);
        bf16x8 bh = *reinterpret_cast<const bf16x8*>(&xsh[prow + blkoff]);
        bf16x8 bl = *reinterpret_cast<const bf16x8*>(&xsl[prow + blkoff]);
        acch = __builtin_amdgcn_mfma_f32_32x32x16_bf16(af[icg], bh, acch, 0, 0, 0);
        accl = __builtin_amdgcn_mfma_f32_32x32x16_bf16(af[icg], bl, accl, 0, 0, 0);
      }
    }
  }
  const int l = l0 + lw + col;
  if (l < LO) {
#pragma unroll
    for (int r = 0; r < 16; ++r) {
      int o = o0 + (r & 3) + 8 * (r >> 2) + 4 * g;
      y1[(b * CO + o) * LO + l] = alphaf[o] * (acch[r] + accl[r]) + bias[o];
    }
  }
}

// ---------------- K2/K3: BN stats (deterministic two-stage)
__global__ __launch_bounds__(256) void k_stats(const float* __restrict__ y1, float* __restrict__ ps,
                                               float* __restrict__ ps2) {
  int o = blockIdx.x, b = blockIdx.y;
  const float* row = y1 + (b * CO + o) * LO;
  float s = 0.f, s2 = 0.f;
  for (int l = threadIdx.x; l < LO; l += 256) {
    float v = row[l];
    s += v;
    s2 += v * v;
  }
  __shared__ float r1[256], r2[256];
  r1[threadIdx.x] = s;
  r2[threadIdx.x] = s2;
  __syncthreads();
  for (int st = 128; st > 0; st >>= 1) {
    if (threadIdx.x < st) {
      r1[threadIdx.x] += r1[threadIdx.x + st];
      r2[threadIdx.x] += r2[threadIdx.x + st];
    }
    __syncthreads();
  }
  if (threadIdx.x == 0) {
    ps[b * CO + o] = r1[0];
    ps2[b * CO + o] = r2[0];
  }
}

__global__ void k_bnparams(const float* __restrict__ ps, const float* __restrict__ ps2,
                           const float* __restrict__ gamma, const float* __restrict__ beta,
                           float* __restrict__ bnsc, float* __restrict__ bnsh) {
  int o = threadIdx.x;
  float s = 0.f, s2 = 0.f;
  for (int b = 0; b < B_; ++b) {
    s += ps[b * CO + o];
    s2 += ps2[b * CO + o];
  }
  const float inv_n = 1.f / (float)(B_ * LO);
  float mu = s * inv_n;
  float var = s2 * inv_n - mu * mu;
  float sc = gamma[o] * rsqrtf(var + 1e-5f);
  bnsc[o] = sc;
  bnsh[o] = beta[o] - mu * sc;
}

// ---------------- K5: Q,K,V projections (BN+ELU fused into staging; bf16x4 split; coalesced wT3)
__global__ __launch_bounds__(256) void k_qkv(const float* __restrict__ y1, const float* __restrict__ bnsc,
                                             const float* __restrict__ bnsh, const u16* __restrict__ wT3,
                                             u16* __restrict__ sq, u16* __restrict__ sk, u16* __restrict__ sv) {
  int tile = blockIdx.x, b = blockIdx.y;
  int tid = threadIdx.x, wave = tid >> 6, lane = tid & 63, n = lane & 15, g = lane >> 4;
  const int t0 = tile * 64;
  alignas(16) __shared__ u16 hshi[64 * 136];
  alignas(16) __shared__ u16 hslo[64 * 136];
  {
    int t = tid & 63;
    int l = t0 + t;
    if (l > LO - 1) l = LO - 1;
    for (int c = (tid >> 6); c < CO; c += 4) {
      float raw = y1[((size_t)b * CO + c) * LO + l];
      float e = elu(raw * bnsc[c] + bnsh[c]);
      u16 hi = f2b(e);
      hshi[t * 136 + c] = hi;
      hslo[t * 136 + c] = f2b(e - b2f(hi));
    }
  }
  __syncthreads();
  const u16* ah = &hshi[(wave * 16 + n) * 136];
  const u16* al = &hslo[(wave * 16 + n) * 136];
  u16* outs[3] = {sq, sk, sv};
  for (int mat = 0; mat < 3; ++mat) {
    f32x4 acc[8] = {};
#pragma unroll
    for (int ks = 0; ks < 4; ++ks) {
      bf16x8 ahi = *reinterpret_cast<const bf16x8*>(ah + ks * 32 + g * 8);
      bf16x8 alo = *reinterpret_cast<const bf16x8*>(al + ks * 32 + g * 8);
      const u16* wbase = wT3 + (size_t)((mat * 4 + ks) * 8) * 1024 + n * 32 + g * 8;
#pragma unroll
      for (int nt = 0; nt < 8; ++nt) {
        bf16x8 bhi = *reinterpret_cast<const bf16x8*>(wbase + nt * 1024);
        bf16x8 blo = *reinterpret_cast<const bf16x8*>(wbase + nt * 1024 + 512);
        acc[nt] = __builtin_amdgcn_mfma_f32_16x16x32_bf16(ahi, bhi, acc[nt], 0, 0, 0);
        acc[nt] = __builtin_amdgcn_mfma_f32_16x16x32_bf16(ahi, blo, acc[nt], 0, 0, 0);
        acc[nt] = __builtin_amdgcn_mfma_f32_16x16x32_bf16(alo, bhi, acc[nt], 0, 0, 0);
        acc[nt] = __builtin_amdgcn_mfma_f32_16x16x32_bf16(alo, blo, acc[nt], 0, 0, 0);
      }
    }
    u16* so = outs[mat];
#pragma unroll
    for (int nt = 0; nt < 8; ++nt) {
#pragma unroll
      for (int r = 0; r < 4; ++r) {
        int tok = t0 + wave * 16 + g * 4 + r;
        int c = nt * 16 + n;
        bool valid = tok < LO;
        float v = valid ? acc[nt][r] : 0.f;
        so[((size_t)b * LP + tok) * CO + c] = f2b(v > 0.f ? 1.f : 0.f);
      }
    }
  }
}

// ---------------- K6: pool (BN+ELU fused) over global-attn chunks. One 64-lane block per (c,b) row.
__global__ __launch_bounds__(64) void k_poolh(const float* __restrict__ y1, const float* __restrict__ bnsc,
                                              const float* __restrict__ bnsh, float* __restrict__ hsum) {
  int c = blockIdx.x, b = blockIdx.y, lane = threadIdx.x;
  const float* row = y1 + ((size_t)b * CO + c) * LO;
  const float sc = bnsc[c], sh = bnsh[c];
  __shared__ float bins[16][64];
#pragma unroll
  for (int ch = 0; ch < 16; ++ch) bins[ch][lane] = 0.f;
  for (int j = lane; j < LO; j += 64) {
    float e = elu(row[j] * sc + sh);
    bins[j / 157][lane] += e;
  }
#pragma unroll
  for (int ch = 0; ch < 16; ++ch) {
    float v = bins[ch][lane];
    for (int off = 32; off > 0; off >>= 1) v += __shfl_down(v, off);
    if (lane == 0) hsum[(b * 16 + ch) * CO + c] = v;
  }
}

// ---------------- K7: pooled K/V spikes (fp32 exact) -> kvT[d][c] = (1/48)*sum_g skg[c]*svg[d]
__global__ __launch_bounds__(256) void k_kv2(const float* __restrict__ hsum, const float* __restrict__ wk,
                                             const float* __restrict__ wv, u16* __restrict__ kvT) {
  int b = blockIdx.x;
  __shared__ float hs[16 * 128], sks[16 * 128], svs[16 * 128];
  for (int i = threadIdx.x; i < 2048; i += 256) hs[i] = hsum[b * 2048 + i];
  __syncthreads();
  for (int idx = threadIdx.x; idx < 2048; idx += 256) {
    int gg = idx >> 7, c = idx & 127;
    float ak = 0.f, av = 0.f;
    for (int k = 0; k < 128; ++k) {
      float hv = hs[gg * 128 + k];
      ak += hv * wk[k * CO + c];
      av += hv * wv[k * CO + c];
    }
    sks[idx] = ak > 0.f ? 1.f : 0.f;
    svs[idx] = av > 0.f ? 1.f : 0.f;
  }
  __syncthreads();
  for (int idx = threadIdx.x; idx < CO * CO; idx += 256) {
    int d = idx >> 7, c = idx & 127;
    float s = 0.f;
#pragma unroll
    for (int gg = 0; gg < 16; ++gg) s += sks[gg * 128 + c] * svs[gg * 128 + d];
    kvT[b * CO * CO + idx] = f2b(s * (1.f / 48.f));
  }
}

// ---------------- K8: fused attention; residual recomputes BN+ELU from raw y1 in epilogue.
__global__ __launch_bounds__(512) void k_attn(const u16* __restrict__ sq, const u16* __restrict__ sk,
                                              const u16* __restrict__ sv, const u16* __restrict__ kvT,
                                              const u16* __restrict__ woT, const float* __restrict__ y1,
                                              const float* __restrict__ bnsc, const float* __restrict__ bnsh,
                                              float* __restrict__ out) {
  const int win = blockIdx.x, b = blockIdx.y, qt = blockIdx.z;
  const int T0 = win * 256;
  __shared__ u16 svT[128 * 264];      // svT[c][u]
  __shared__ u16 plds[8 * 16 * 264];  // per-wave [16 q][264 u] scratch (P, then attn-out)
  const int tid = threadIdx.x, wave = tid >> 6, lane = tid & 63, n = lane & 15, g = lane >> 4;
  for (int idx = tid; idx < 256 * 128; idx += 512) {
    int u = idx >> 7, c = idx & 127;
    svT[c * 264 + u] = sv[((size_t)b * LP + T0 + u) * CO + c];
  }
  __syncthreads();
  u16* pw = plds + wave * 16 * 264;
  {
    const int qbase = wave * 32 + qt * 16;
    bf16x8 bq[4];
    const u16* qrow = sq + ((size_t)b * LP + T0 + qbase + n) * CO;
#pragma unroll
    for (int ks = 0; ks < 4; ++ks) bq[ks] = *reinterpret_cast<const bf16x8*>(qrow + ks * 32 + g * 8);
    // phase A: S^T[u][q] = sum_k sk[u][k] * sq[q][k]
    f32x4 pacc[16];
#pragma unroll
    for (int ut = 0; ut < 16; ++ut) pacc[ut] = f32x4{0.f, 0.f, 0.f, 0.f};
    for (int ut = 0; ut < 16; ++ut) {
      const u16* krow = sk + ((size_t)b * LP + T0 + ut * 16 + n) * CO;
#pragma unroll
      for (int ks = 0; ks < 4; ++ks) {
        bf16x8 af = *reinterpret_cast<const bf16x8*>(krow + ks * 32 + g * 8);
        pacc[ut] = __builtin_amdgcn_mfma_f32_16x16x32_bf16(af, bq[ks], pacc[ut], 0, 0, 0);
      }
    }
    // phase A2: window weights (1/768 + 1/192 on diagonal 64-blocks), pack to LDS
    const int qloc = qbase + n;
    const int qblk = qloc >> 6;
#pragma unroll
    for (int ut = 0; ut < 16; ++ut) {
      u16 pk[4];
#pragma unroll
      for (int r = 0; r < 4; ++r) {
        int uloc = ut * 16 + g * 4 + r;
        float wgt = (1.f / 768.f) + (((uloc >> 6) == qblk) ? (1.f / 192.f) : 0.f);
        pk[r] = f2b(pacc[ut][r] * wgt);
      }
      unsigned long long pk64 = (unsigned long long)pk[0] | ((unsigned long long)pk[1] << 16) |
                                ((unsigned long long)pk[2] << 32) | ((unsigned long long)pk[3] << 48);
      *reinterpret_cast<unsigned long long*>(&pw[n * 264 + ut * 16 + g * 4]) = pk64;
    }
    __syncthreads();
    // phase B: PV (weighted); phase C: + global attn (kvT premultiplied by 1/48)
    f32x4 acco[8] = {};
    for (int us = 0; us < 8; ++us) {
      bf16x8 pa = *reinterpret_cast<const bf16x8*>(&pw[n * 264 + us * 32 + g * 8]);
#pragma unroll
      for (int ct = 0; ct < 8; ++ct) {
        bf16x8 bv = *reinterpret_cast<const bf16x8*>(&svT[(ct * 16 + n) * 264 + us * 32 + g * 8]);
        acco[ct] = __builtin_amdgcn_mfma_f32_16x16x32_bf16(pa, bv, acco[ct], 0, 0, 0);
      }
    }
#pragma unroll
    for (int ks = 0; ks < 4; ++ks) {
#pragma unroll
      for (int ct = 0; ct < 8; ++ct) {
        bf16x8 bkv = *reinterpret_cast<const bf16x8*>(kvT + ((size_t)b * CO + ct * 16 + n) * CO + ks * 32 + g * 8);
        acco[ct] = __builtin_amdgcn_mfma_f32_16x16x32_bf16(bq[ks], bkv, acco[ct], 0, 0, 0);
      }
    }
    // phase D: attn-out tile -> LDS (bf16)
#pragma unroll
    for (int ct = 0; ct < 8; ++ct) {
#pragma unroll
      for (int r = 0; r < 4; ++r) {
        pw[(g * 4 + r) * 264 + ct * 16 + n] = f2b(acco[ct][r]);
      }
    }
    __syncthreads();
    // phase E: y = elu(bn(y1)) + out@wo, store (B, Co, Lo)
#pragma unroll
    for (int ot = 0; ot < 8; ++ot) {
      f32x4 facc = {};
#pragma unroll
      for (int ks = 0; ks < 4; ++ks) {
        bf16x8 af = *reinterpret_cast<const bf16x8*>(&pw[n * 264 + ks * 32 + g * 8]);
        bf16x8 bw = *reinterpret_cast<const bf16x8*>(woT + (ot * 16 + n) * CO + ks * 32 + g * 8);
        facc = __builtin_amdgcn_mfma_f32_16x16x32_bf16(af, bw, facc, 0, 0, 0);
      }
      int o = ot * 16 + n;
      float sc = bnsc[o], sh = bnsh[o];
      int lb = T0 + qbase + g * 4;
#pragma unroll
      for (int r = 0; r < 4; ++r) {
        int l = lb + r;
        if (l < LO) {
          size_t idx = ((size_t)b * CO + o) * LO + l;
          out[idx] = elu(y1[idx] * sc + sh) + facc[r];
        }
      }
    }
  }
}

extern "C" void kernel_launch(void* const* d_in, const int* in_sizes, int n_in, void* d_out, int out_size,
                              void* d_ws, size_t ws_size, hipStream_t stream) {
  const float* x = (const float*)d_in[0];
  const float* conv_w = (const float*)d_in[1];
  const float* conv_b = (const float*)d_in[2];
  const float* gamma = (const float*)d_in[3];
  const float* beta = (const float*)d_in[4];
  const float* wq = (const float*)d_in[5];
  const float* wk = (const float*)d_in[6];
  const float* wv = (const float*)d_in[7];
  const float* wo = (const float*)d_in[8];
  (void)in_sizes; (void)n_in; (void)out_size; (void)ws_size;

  char* ws = (char*)d_ws;
  size_t off = 0;
  auto alloc = [&](size_t bytes) -> void* {
    void* p = ws + off;
    off += (bytes + 511) & ~(size_t)511;
    return p;
  };
  float* ps = (float*)alloc((size_t)B_ * CO * 4);
  float* ps2 = (float*)alloc((size_t)B_ * CO * 4);
  float* bnsc = (float*)alloc(CO * 4);
  float* bnsh = (float*)alloc(CO * 4);
  float* alphaf = (float*)alloc(CO * 4);
  float* hsum = (float*)alloc((size_t)B_ * 16 * CO * 4);
  u16* kvT = (u16*)alloc((size_t)B_ * CO * CO * 2);
  u16* wfmt = (u16*)alloc((size_t)CO * KW * CI * 2);
  u16* wThi = (u16*)alloc((size_t)4 * CO * CO * 2);
  u16* wTlo = (u16*)alloc((size_t)4 * CO * CO * 2);
  u16* wT3 = (u16*)alloc((size_t)3 * 4 * 8 * 1024 * 2);
  float* y1 = (float*)alloc((size_t)B_ * CO * LO * 4);
  u16* sqb = (u16*)alloc((size_t)B_ * LP * CO * 2);
  u16* skb = (u16*)alloc((size_t)B_ * LP * CO * 2);
  u16* svb = (u16*)alloc((size_t)B_ * LP * CO * 2);

  hipLaunchKernelGGL(k_prep_wq, dim3(CO), dim3(256), 0, stream, conv_w, wfmt, alphaf);
  hipLaunchKernelGGL(k_prep_wT, dim3(4), dim3(256), 0, stream, wq, wk, wv, wo, wThi, wTlo, wT3);
  hipLaunchKernelGGL(k_conv, dim3(40, B_), dim3(512), 0, stream, x, wfmt, conv_b, alphaf, y1);
  hipLaunchKernelGGL(k_stats, dim3(CO, B_), dim3(256), 0, stream, y1, ps, ps2);
  hipLaunchKernelGGL(k_bnparams, dim3(1), dim3(CO), 0, stream, ps, ps2, gamma, beta, bnsc, bnsh);
  hipLaunchKernelGGL(k_qkv, dim3(40, B_), dim3(256), 0, stream, y1, bnsc, bnsh, wT3, sqb, skb, svb);
  hipLaunchKernelGGL(k_poolh, dim3(CO, B_), dim3(64), 0, stream, y1, bnsc, bnsh, hsum);
  hipLaunchKernelGGL(k_kv2, dim3(B_), dim3(256), 0, stream, hsum, wk, wv, kvT);
  hipLaunchKernelGGL(k_attn, dim3(10, B_, 2), dim3(512), 0, stream, sqb, skb, svb, kvT, wThi + 3 * CO * CO, y1,
                     bnsc, bnsh, (float*)d_out);
}